// Round 1
// baseline (212.408 us; speedup 1.0000x reference)
//
#include <hip/hip_runtime.h>
#include <math.h>

#define GEO_N 256

__device__ __forceinline__ float wredf(float v) {
#pragma unroll
  for (int off = 32; off; off >>= 1) v += __shfl_xor(v, off, 64);
  return v;
}

// One Jacobi rotation on symmetric G (both sides) + accumulate into V.
// Template indices guarantee compile-time register addressing (no scratch).
template <int P, int Q>
__device__ __forceinline__ void jrot(float G[3][3], float V[3][3]) {
  float apq = G[P][Q];
  if (fabsf(apq) < 1e-22f) return;
  float tau = (G[Q][Q] - G[P][P]) / (2.0f * apq);
  float tt = sqrtf(1.0f + tau * tau);
  float t = (tau >= 0.0f) ? (1.0f / (tau + tt)) : (1.0f / (tau - tt));
  float c = 1.0f / sqrtf(1.0f + t * t);
  float s = t * c;
#pragma unroll
  for (int k = 0; k < 3; ++k) {
    float gkp = G[k][P], gkq = G[k][Q];
    G[k][P] = c * gkp - s * gkq;
    G[k][Q] = s * gkp + c * gkq;
  }
#pragma unroll
  for (int k = 0; k < 3; ++k) {
    float gpk = G[P][k], gqk = G[Q][k];
    G[P][k] = c * gpk - s * gqk;
    G[Q][k] = s * gpk + c * gqk;
  }
#pragma unroll
  for (int k = 0; k < 3; ++k) {
    float vkp = V[k][P], vkq = V[k][Q];
    V[k][P] = c * vkp - s * vkq;
    V[k][Q] = s * vkp + c * vkq;
  }
}

__global__ __launch_bounds__(256) void geo_main(const float* __restrict__ kp,
                                                const int* __restrict__ perm,
                                                float* __restrict__ partials,
                                                double* __restrict__ atom) {
  const int b = blockIdx.x;
  const int t = threadIdx.x;
  const int lane = t & 63, wv = t >> 6;

  const size_t sbase = ((size_t)b * GEO_N + t) * 3;
  const int pb = perm[b];
  const size_t dbase = ((size_t)pb * GEO_N + t) * 3;
  const float sx = kp[sbase + 0], sy = kp[sbase + 1], sz = kp[sbase + 2];
  const float dx = kp[dbase + 0], dy = kp[dbase + 1], dz = kp[dbase + 2];

  // 16 moments: Ssrc(3) Sdst(3) M_ij = sum dst_i*src_j (9) q = sum|src|^2 (1)
  float r[16] = {sx, sy, sz, dx, dy, dz,
                 dx * sx, dx * sy, dx * sz,
                 dy * sx, dy * sy, dy * sz,
                 dz * sx, dz * sy, dz * sz,
                 sx * sx + sy * sy + sz * sz};
#pragma unroll
  for (int k = 0; k < 16; ++k) r[k] = wredf(r[k]);

  __shared__ float red[4][16];
  if (lane == 0) {
#pragma unroll
    for (int k = 0; k < 16; ++k) red[wv][k] = r[k];
  }
  __syncthreads();

  __shared__ float bc[13];  // R(9), scale, T(3)
  if (t == 0) {
    float s0[16];
#pragma unroll
    for (int k = 0; k < 16; ++k) s0[k] = (red[0][k] + red[1][k]) + (red[2][k] + red[3][k]);
    const float invN = 1.0f / (float)GEO_N;
    const float smx = s0[0] * invN, smy = s0[1] * invN, smz = s0[2] * invN;
    const float dmx = s0[3] * invN, dmy = s0[4] * invN, dmz = s0[5] * invN;
    float A[3][3];
    A[0][0] = s0[6] * invN - dmx * smx;  A[0][1] = s0[7] * invN - dmx * smy;  A[0][2] = s0[8] * invN - dmx * smz;
    A[1][0] = s0[9] * invN - dmy * smx;  A[1][1] = s0[10] * invN - dmy * smy; A[1][2] = s0[11] * invN - dmy * smz;
    A[2][0] = s0[12] * invN - dmz * smx; A[2][1] = s0[13] * invN - dmz * smy; A[2][2] = s0[14] * invN - dmz * smz;
    const float var_sum = s0[15] * invN - (smx * smx + smy * smy + smz * smz);

    // G = A^T A (symmetric PSD), Jacobi eigensolve -> V, lambda
    float G[3][3];
#pragma unroll
    for (int i = 0; i < 3; ++i)
#pragma unroll
      for (int j = 0; j < 3; ++j)
        G[i][j] = A[0][i] * A[0][j] + A[1][i] * A[1][j] + A[2][i] * A[2][j];
    float V[3][3] = {{1, 0, 0}, {0, 1, 0}, {0, 0, 1}};
#pragma unroll 1
    for (int sweep = 0; sweep < 8; ++sweep) {
      float off = G[0][1] * G[0][1] + G[0][2] * G[0][2] + G[1][2] * G[1][2];
      float dia = G[0][0] * G[0][0] + G[1][1] * G[1][1] + G[2][2] * G[2][2];
      if (off <= 1e-13f * dia + 1e-30f) break;
      jrot<0, 1>(G, V);
      jrot<0, 2>(G, V);
      jrot<1, 2>(G, V);
    }
    float l0 = G[0][0], l1 = G[1][1], l2 = G[2][2];
    // sort eigenpairs descending, swapping V columns (compile-time indices)
    if (l0 < l1) { float tl = l0; l0 = l1; l1 = tl;
#pragma unroll
      for (int k = 0; k < 3; ++k) { float tv = V[k][0]; V[k][0] = V[k][1]; V[k][1] = tv; } }
    if (l0 < l2) { float tl = l0; l0 = l2; l2 = tl;
#pragma unroll
      for (int k = 0; k < 3; ++k) { float tv = V[k][0]; V[k][0] = V[k][2]; V[k][2] = tv; } }
    if (l1 < l2) { float tl = l1; l1 = l2; l2 = tl;
#pragma unroll
      for (int k = 0; k < 3; ++k) { float tv = V[k][1]; V[k][1] = V[k][2]; V[k][2] = tv; } }
    const float sig0 = sqrtf(fmaxf(l0, 0.0f));
    const float sig1 = sqrtf(fmaxf(l1, 0.0f));
    const float sig2 = sqrtf(fmaxf(l2, 0.0f));

    float v0[3] = {V[0][0], V[1][0], V[2][0]};
    float v1[3] = {V[0][1], V[1][1], V[2][1]};
    float v2[3] = {V[0][2], V[1][2], V[2][2]};
    float u0[3], u1[3], u2r[3];
#pragma unroll
    for (int i = 0; i < 3; ++i) {
      u0[i]  = A[i][0] * v0[0] + A[i][1] * v0[1] + A[i][2] * v0[2];
      u1[i]  = A[i][0] * v1[0] + A[i][1] * v1[1] + A[i][2] * v1[2];
      u2r[i] = A[i][0] * v2[0] + A[i][1] * v2[1] + A[i][2] * v2[2];
    }
    // u0 = normalize(A v0)
    float n0 = u0[0] * u0[0] + u0[1] * u0[1] + u0[2] * u0[2];
    if (n0 > 1e-28f) { float inv = 1.0f / sqrtf(n0); u0[0] *= inv; u0[1] *= inv; u0[2] *= inv; }
    else { u0[0] = 1.0f; u0[1] = 0.0f; u0[2] = 0.0f; }
    // u1 = normalize(A v1 - proj_u0)
    float d01 = u1[0] * u0[0] + u1[1] * u0[1] + u1[2] * u0[2];
    u1[0] -= d01 * u0[0]; u1[1] -= d01 * u0[1]; u1[2] -= d01 * u0[2];
    float n1 = u1[0] * u1[0] + u1[1] * u1[1] + u1[2] * u1[2];
    if (n1 > 1e-28f) { float inv = 1.0f / sqrtf(n1); u1[0] *= inv; u1[1] *= inv; u1[2] *= inv; }
    else {
      float ex[3] = {1, 0, 0}, ey[3] = {0, 1, 0};
      const float* e = (fabsf(u0[0]) < 0.9f) ? ex : ey;
      u1[0] = u0[1] * e[2] - u0[2] * e[1];
      u1[1] = u0[2] * e[0] - u0[0] * e[2];
      u1[2] = u0[0] * e[1] - u0[1] * e[0];
      float nn = u1[0] * u1[0] + u1[1] * u1[1] + u1[2] * u1[2];
      float inv = 1.0f / sqrtf(nn);
      u1[0] *= inv; u1[1] *= inv; u1[2] *= inv;
    }
    // u2 = cross(u0,u1), sign matched to A v2 (polar-factor pairing)
    float u2[3] = {u0[1] * u1[2] - u0[2] * u1[1],
                   u0[2] * u1[0] - u0[0] * u1[2],
                   u0[0] * u1[1] - u0[1] * u1[0]};
    float d2 = u2[0] * u2r[0] + u2[1] * u2r[1] + u2[2] * u2r[2];
    if (d2 < 0.0f) { u2[0] = -u2[0]; u2[1] = -u2[1]; u2[2] = -u2[2]; }

    const float scale = (sig0 + sig1 + sig2) / fmaxf(var_sum, 1e-30f);
    float R[3][3];
#pragma unroll
    for (int i = 0; i < 3; ++i)
#pragma unroll
      for (int j = 0; j < 3; ++j)
        R[i][j] = u0[i] * v0[j] + u1[i] * v1[j] + u2[i] * v2[j];
    const float Tx = dmx - scale * (R[0][0] * smx + R[0][1] * smy + R[0][2] * smz);
    const float Ty = dmy - scale * (R[1][0] * smx + R[1][1] * smy + R[1][2] * smz);
    const float Tz = dmz - scale * (R[2][0] * smx + R[2][1] * smy + R[2][2] * smz);
#pragma unroll
    for (int i = 0; i < 3; ++i)
#pragma unroll
      for (int j = 0; j < 3; ++j) bc[3 * i + j] = R[i][j];
    bc[9] = scale; bc[10] = Tx; bc[11] = Ty; bc[12] = Tz;
  }
  __syncthreads();

  const float sc = bc[9];
  const float e0 = sc * (bc[0] * sx + bc[1] * sy + bc[2] * sz) + bc[10] - dx;
  const float e1 = sc * (bc[3] * sx + bc[4] * sy + bc[5] * sz) + bc[11] - dy;
  const float e2 = sc * (bc[6] * sx + bc[7] * sy + bc[8] * sz) + bc[12] - dz;
  float acc = fabsf(e0) + fabsf(e1) + fabsf(e2);
  acc = wredf(acc);

  __shared__ float red2[4];
  if (lane == 0) red2[wv] = acc;
  __syncthreads();
  if (t == 0) {
    float bs = (red2[0] + red2[1]) + (red2[2] + red2[3]);
    if (partials) partials[b] = bs;
    else atomicAdd(atom, (double)bs);
  }
}

__global__ __launch_bounds__(1024) void geo_fin(const float* __restrict__ partials,
                                                float* __restrict__ out, int n,
                                                double inv_total) {
  const int t = threadIdx.x;
  double acc = 0.0;
  for (int i = t; i < n; i += 1024) acc += (double)partials[i];
#pragma unroll
  for (int off = 32; off; off >>= 1) acc += __shfl_xor(acc, off, 64);
  __shared__ double sred[16];
  if ((t & 63) == 0) sred[t >> 6] = acc;
  __syncthreads();
  if (t == 0) {
    double tot = 0.0;
#pragma unroll
    for (int k = 0; k < 16; ++k) tot += sred[k];
    out[0] = (float)(tot * inv_total);
  }
}

__global__ void geo_zero(double* a) { *a = 0.0; }

__global__ void geo_fin_atomic(const double* __restrict__ a, float* __restrict__ out,
                               double inv_total) {
  out[0] = (float)(a[0] * inv_total);
}

extern "C" void kernel_launch(void* const* d_in, const int* in_sizes, int n_in,
                              void* d_out, int out_size, void* d_ws, size_t ws_size,
                              hipStream_t stream) {
  const float* kp = (const float*)d_in[0];
  const int* perm = (const int*)d_in[1];
  float* out = (float*)d_out;
  const int B = in_sizes[1];  // 32768 batches
  const double inv_total = 1.0 / ((double)B * (double)GEO_N * 3.0);

  if (ws_size >= (size_t)B * sizeof(float)) {
    // Deterministic path: one fp32 partial per batch, fp64 tree-reduce.
    float* partials = (float*)d_ws;
    geo_main<<<B, 256, 0, stream>>>(kp, perm, partials, nullptr);
    geo_fin<<<1, 1024, 0, stream>>>(partials, out, B, inv_total);
  } else {
    // Fallback: single fp64 accumulator.
    double* acc = (double*)d_ws;
    geo_zero<<<1, 1, 0, stream>>>(acc);
    geo_main<<<B, 256, 0, stream>>>(kp, perm, nullptr, acc);
    geo_fin_atomic<<<1, 1, 0, stream>>>(acc, out, inv_total);
  }
}

// Round 2
// 87.382 us; speedup vs baseline: 2.4308x; 2.4308x over previous
//
#include <hip/hip_runtime.h>
#include <math.h>

#define GEO_N 256

__device__ __forceinline__ float wredf(float v) {
#pragma unroll
  for (int off = 32; off; off >>= 1) v += __shfl_xor(v, off, 64);
  return v;
}

// One Jacobi rotation on symmetric G (both sides) + accumulate into V.
template <int P, int Q>
__device__ __forceinline__ void jrot(float G[3][3], float V[3][3]) {
  float apq = G[P][Q];
  if (fabsf(apq) < 1e-22f) return;
  float tau = (G[Q][Q] - G[P][P]) / (2.0f * apq);
  float tt = sqrtf(1.0f + tau * tau);
  float t = (tau >= 0.0f) ? (1.0f / (tau + tt)) : (1.0f / (tau - tt));
  float c = 1.0f / sqrtf(1.0f + t * t);
  float s = t * c;
#pragma unroll
  for (int k = 0; k < 3; ++k) {
    float gkp = G[k][P], gkq = G[k][Q];
    G[k][P] = c * gkp - s * gkq;
    G[k][Q] = s * gkp + c * gkq;
  }
#pragma unroll
  for (int k = 0; k < 3; ++k) {
    float gpk = G[P][k], gqk = G[Q][k];
    G[P][k] = c * gpk - s * gqk;
    G[Q][k] = s * gpk + c * gqk;
  }
#pragma unroll
  for (int k = 0; k < 3; ++k) {
    float vkp = V[k][P], vkq = V[k][Q];
    V[k][P] = c * vkp - s * vkq;
    V[k][Q] = s * vkp + c * vkq;
  }
}

// From 16 raw moment sums -> R(9), scale, T(3) packed into bc[0..12].
// s0: Ssrc(3) Sdst(3) M_ij=sum dst_i*src_j (9, row-major i) q=sum|src|^2 (1)
__device__ __forceinline__ void solve_rst(const float s0[16], float bc[16]) {
  const float invN = 1.0f / (float)GEO_N;
  const float smx = s0[0] * invN, smy = s0[1] * invN, smz = s0[2] * invN;
  const float dmx = s0[3] * invN, dmy = s0[4] * invN, dmz = s0[5] * invN;
  float A[3][3];
  A[0][0] = s0[6] * invN - dmx * smx;  A[0][1] = s0[7] * invN - dmx * smy;  A[0][2] = s0[8] * invN - dmx * smz;
  A[1][0] = s0[9] * invN - dmy * smx;  A[1][1] = s0[10] * invN - dmy * smy; A[1][2] = s0[11] * invN - dmy * smz;
  A[2][0] = s0[12] * invN - dmz * smx; A[2][1] = s0[13] * invN - dmz * smy; A[2][2] = s0[14] * invN - dmz * smz;
  const float var_sum = s0[15] * invN - (smx * smx + smy * smy + smz * smz);

  // G = A^T A (symmetric PSD), Jacobi eigensolve -> V, lambda
  float G[3][3];
#pragma unroll
  for (int i = 0; i < 3; ++i)
#pragma unroll
    for (int j = 0; j < 3; ++j)
      G[i][j] = A[0][i] * A[0][j] + A[1][i] * A[1][j] + A[2][i] * A[2][j];
  float V[3][3] = {{1, 0, 0}, {0, 1, 0}, {0, 0, 1}};
#pragma unroll 1
  for (int sweep = 0; sweep < 8; ++sweep) {
    float off = G[0][1] * G[0][1] + G[0][2] * G[0][2] + G[1][2] * G[1][2];
    float dia = G[0][0] * G[0][0] + G[1][1] * G[1][1] + G[2][2] * G[2][2];
    if (off <= 1e-13f * dia + 1e-30f) break;
    jrot<0, 1>(G, V);
    jrot<0, 2>(G, V);
    jrot<1, 2>(G, V);
  }
  float l0 = G[0][0], l1 = G[1][1], l2 = G[2][2];
  if (l0 < l1) { float tl = l0; l0 = l1; l1 = tl;
#pragma unroll
    for (int k = 0; k < 3; ++k) { float tv = V[k][0]; V[k][0] = V[k][1]; V[k][1] = tv; } }
  if (l0 < l2) { float tl = l0; l0 = l2; l2 = tl;
#pragma unroll
    for (int k = 0; k < 3; ++k) { float tv = V[k][0]; V[k][0] = V[k][2]; V[k][2] = tv; } }
  if (l1 < l2) { float tl = l1; l1 = l2; l2 = tl;
#pragma unroll
    for (int k = 0; k < 3; ++k) { float tv = V[k][1]; V[k][1] = V[k][2]; V[k][2] = tv; } }
  const float sig0 = sqrtf(fmaxf(l0, 0.0f));
  const float sig1 = sqrtf(fmaxf(l1, 0.0f));
  const float sig2 = sqrtf(fmaxf(l2, 0.0f));

  float v0[3] = {V[0][0], V[1][0], V[2][0]};
  float v1[3] = {V[0][1], V[1][1], V[2][1]};
  float v2[3] = {V[0][2], V[1][2], V[2][2]};
  float u0[3], u1[3], u2r[3];
#pragma unroll
  for (int i = 0; i < 3; ++i) {
    u0[i]  = A[i][0] * v0[0] + A[i][1] * v0[1] + A[i][2] * v0[2];
    u1[i]  = A[i][0] * v1[0] + A[i][1] * v1[1] + A[i][2] * v1[2];
    u2r[i] = A[i][0] * v2[0] + A[i][1] * v2[1] + A[i][2] * v2[2];
  }
  float n0 = u0[0] * u0[0] + u0[1] * u0[1] + u0[2] * u0[2];
  if (n0 > 1e-28f) { float inv = 1.0f / sqrtf(n0); u0[0] *= inv; u0[1] *= inv; u0[2] *= inv; }
  else { u0[0] = 1.0f; u0[1] = 0.0f; u0[2] = 0.0f; }
  float d01 = u1[0] * u0[0] + u1[1] * u0[1] + u1[2] * u0[2];
  u1[0] -= d01 * u0[0]; u1[1] -= d01 * u0[1]; u1[2] -= d01 * u0[2];
  float n1 = u1[0] * u1[0] + u1[1] * u1[1] + u1[2] * u1[2];
  if (n1 > 1e-28f) { float inv = 1.0f / sqrtf(n1); u1[0] *= inv; u1[1] *= inv; u1[2] *= inv; }
  else {
    float ex[3] = {1, 0, 0}, ey[3] = {0, 1, 0};
    const float* e = (fabsf(u0[0]) < 0.9f) ? ex : ey;
    u1[0] = u0[1] * e[2] - u0[2] * e[1];
    u1[1] = u0[2] * e[0] - u0[0] * e[2];
    u1[2] = u0[0] * e[1] - u0[1] * e[0];
    float nn = u1[0] * u1[0] + u1[1] * u1[1] + u1[2] * u1[2];
    float inv = 1.0f / sqrtf(nn);
    u1[0] *= inv; u1[1] *= inv; u1[2] *= inv;
  }
  float u2[3] = {u0[1] * u1[2] - u0[2] * u1[1],
                 u0[2] * u1[0] - u0[0] * u1[2],
                 u0[0] * u1[1] - u0[1] * u1[0]};
  float d2 = u2[0] * u2r[0] + u2[1] * u2r[1] + u2[2] * u2r[2];
  if (d2 < 0.0f) { u2[0] = -u2[0]; u2[1] = -u2[1]; u2[2] = -u2[2]; }

  const float scale = (sig0 + sig1 + sig2) / fmaxf(var_sum, 1e-30f);
  float R[3][3];
#pragma unroll
  for (int i = 0; i < 3; ++i)
#pragma unroll
    for (int j = 0; j < 3; ++j)
      R[i][j] = u0[i] * v0[j] + u1[i] * v1[j] + u2[i] * v2[j];
  const float Tx = dmx - scale * (R[0][0] * smx + R[0][1] * smy + R[0][2] * smz);
  const float Ty = dmy - scale * (R[1][0] * smx + R[1][1] * smy + R[1][2] * smz);
  const float Tz = dmz - scale * (R[2][0] * smx + R[2][1] * smy + R[2][2] * smz);
#pragma unroll
  for (int i = 0; i < 3; ++i)
#pragma unroll
    for (int j = 0; j < 3; ++j) bc[3 * i + j] = R[i][j];
  bc[9] = scale; bc[10] = Tx; bc[11] = Ty; bc[12] = Tz;
  bc[13] = 0.0f; bc[14] = 0.0f; bc[15] = 0.0f;
}

// ---------- Kernel A: per-batch 16 moments. One wave per batch. ----------
__global__ __launch_bounds__(256) void geo_moments(const float* __restrict__ kp,
                                                   const int* __restrict__ perm,
                                                   float* __restrict__ moments, int B) {
  const int wave = (blockIdx.x << 2) | (threadIdx.x >> 6);
  if (wave >= B) return;
  const int lane = threadIdx.x & 63;
  const float4* s4 = (const float4*)kp + (size_t)wave * 192 + lane * 3;
  const float4* d4 = (const float4*)kp + (size_t)perm[wave] * 192 + lane * 3;
  const float4 a0 = s4[0], a1 = s4[1], a2 = s4[2];
  const float4 b0 = d4[0], b1 = d4[1], b2 = d4[2];
  const float s[12] = {a0.x, a0.y, a0.z, a0.w, a1.x, a1.y, a1.z, a1.w, a2.x, a2.y, a2.z, a2.w};
  const float d[12] = {b0.x, b0.y, b0.z, b0.w, b1.x, b1.y, b1.z, b1.w, b2.x, b2.y, b2.z, b2.w};

  float r[16];
#pragma unroll
  for (int k = 0; k < 16; ++k) r[k] = 0.0f;
#pragma unroll
  for (int p = 0; p < 4; ++p) {
    const float sx = s[3 * p + 0], sy = s[3 * p + 1], sz = s[3 * p + 2];
    const float dx = d[3 * p + 0], dy = d[3 * p + 1], dz = d[3 * p + 2];
    r[0] += sx; r[1] += sy; r[2] += sz;
    r[3] += dx; r[4] += dy; r[5] += dz;
    r[6] += dx * sx; r[7] += dx * sy; r[8] += dx * sz;
    r[9] += dy * sx; r[10] += dy * sy; r[11] += dy * sz;
    r[12] += dz * sx; r[13] += dz * sy; r[14] += dz * sz;
    r[15] += sx * sx + sy * sy + sz * sz;
  }
#pragma unroll
  for (int k = 0; k < 16; ++k) r[k] = wredf(r[k]);
  if (lane == 0) {
    float4* m4 = (float4*)moments + (size_t)wave * 4;
    m4[0] = make_float4(r[0], r[1], r[2], r[3]);
    m4[1] = make_float4(r[4], r[5], r[6], r[7]);
    m4[2] = make_float4(r[8], r[9], r[10], r[11]);
    m4[3] = make_float4(r[12], r[13], r[14], r[15]);
  }
}

// ---------- Kernel B: one THREAD per batch computes R/scale/T. ----------
__global__ __launch_bounds__(256) void geo_svd(const float* __restrict__ moments,
                                               float* __restrict__ params, int B) {
  const int b = blockIdx.x * 256 + threadIdx.x;
  if (b >= B) return;
  const float4* m4 = (const float4*)moments + (size_t)b * 4;
  const float4 m0 = m4[0], m1 = m4[1], m2 = m4[2], m3 = m4[3];
  const float s0[16] = {m0.x, m0.y, m0.z, m0.w, m1.x, m1.y, m1.z, m1.w,
                        m2.x, m2.y, m2.z, m2.w, m3.x, m3.y, m3.z, m3.w};
  float bc[16];
  solve_rst(s0, bc);
  float4* p4 = (float4*)params + (size_t)b * 4;
  p4[0] = make_float4(bc[0], bc[1], bc[2], bc[3]);
  p4[1] = make_float4(bc[4], bc[5], bc[6], bc[7]);
  p4[2] = make_float4(bc[8], bc[9], bc[10], bc[11]);
  p4[3] = make_float4(bc[12], bc[13], bc[14], bc[15]);
}

// ---------- Kernel C: per-batch error sum. One wave per batch. ----------
__global__ __launch_bounds__(256) void geo_err(const float* __restrict__ kp,
                                               const int* __restrict__ perm,
                                               const float* __restrict__ params,
                                               float* __restrict__ partials, int B) {
  const int wave = (blockIdx.x << 2) | (threadIdx.x >> 6);
  if (wave >= B) return;
  const int lane = threadIdx.x & 63;
  const float4* s4 = (const float4*)kp + (size_t)wave * 192 + lane * 3;
  const float4* d4 = (const float4*)kp + (size_t)perm[wave] * 192 + lane * 3;
  const float4 a0 = s4[0], a1 = s4[1], a2 = s4[2];
  const float4 b0 = d4[0], b1 = d4[1], b2 = d4[2];
  const float s[12] = {a0.x, a0.y, a0.z, a0.w, a1.x, a1.y, a1.z, a1.w, a2.x, a2.y, a2.z, a2.w};
  const float d[12] = {b0.x, b0.y, b0.z, b0.w, b1.x, b1.y, b1.z, b1.w, b2.x, b2.y, b2.z, b2.w};

  const float* P = params + (size_t)wave * 16;
  const float R00 = P[0], R01 = P[1], R02 = P[2];
  const float R10 = P[3], R11 = P[4], R12 = P[5];
  const float R20 = P[6], R21 = P[7], R22 = P[8];
  const float sc = P[9], Tx = P[10], Ty = P[11], Tz = P[12];

  float acc = 0.0f;
#pragma unroll
  for (int p = 0; p < 4; ++p) {
    const float sx = s[3 * p + 0], sy = s[3 * p + 1], sz = s[3 * p + 2];
    const float dx = d[3 * p + 0], dy = d[3 * p + 1], dz = d[3 * p + 2];
    const float e0 = sc * (R00 * sx + R01 * sy + R02 * sz) + Tx - dx;
    const float e1 = sc * (R10 * sx + R11 * sy + R12 * sz) + Ty - dy;
    const float e2 = sc * (R20 * sx + R21 * sy + R22 * sz) + Tz - dz;
    acc += fabsf(e0) + fabsf(e1) + fabsf(e2);
  }
  acc = wredf(acc);
  if (lane == 0) partials[wave] = acc;
}

// ---------- Final reduce ----------
__global__ __launch_bounds__(1024) void geo_fin(const float* __restrict__ partials,
                                                float* __restrict__ out, int n,
                                                double inv_total) {
  const int t = threadIdx.x;
  double acc = 0.0;
  for (int i = t; i < n; i += 1024) acc += (double)partials[i];
#pragma unroll
  for (int off = 32; off; off >>= 1) acc += __shfl_xor(acc, off, 64);
  __shared__ double sred[16];
  if ((t & 63) == 0) sred[t >> 6] = acc;
  __syncthreads();
  if (t == 0) {
    double tot = 0.0;
#pragma unroll
    for (int k = 0; k < 16; ++k) tot += sred[k];
    out[0] = (float)(tot * inv_total);
  }
}

// ---------- Fallback (round-1 proven fused kernel) if ws is tiny ----------
__global__ __launch_bounds__(256) void geo_fused(const float* __restrict__ kp,
                                                 const int* __restrict__ perm,
                                                 float* __restrict__ partials) {
  const int b = blockIdx.x;
  const int t = threadIdx.x;
  const int lane = t & 63, wv = t >> 6;
  const size_t sbase = ((size_t)b * GEO_N + t) * 3;
  const int pb = perm[b];
  const size_t dbase = ((size_t)pb * GEO_N + t) * 3;
  const float sx = kp[sbase + 0], sy = kp[sbase + 1], sz = kp[sbase + 2];
  const float dx = kp[dbase + 0], dy = kp[dbase + 1], dz = kp[dbase + 2];
  float r[16] = {sx, sy, sz, dx, dy, dz,
                 dx * sx, dx * sy, dx * sz,
                 dy * sx, dy * sy, dy * sz,
                 dz * sx, dz * sy, dz * sz,
                 sx * sx + sy * sy + sz * sz};
#pragma unroll
  for (int k = 0; k < 16; ++k) r[k] = wredf(r[k]);
  __shared__ float red[4][16];
  if (lane == 0) {
#pragma unroll
    for (int k = 0; k < 16; ++k) red[wv][k] = r[k];
  }
  __syncthreads();
  __shared__ float bcs[16];
  if (t == 0) {
    float s0[16];
#pragma unroll
    for (int k = 0; k < 16; ++k) s0[k] = (red[0][k] + red[1][k]) + (red[2][k] + red[3][k]);
    float bc[16];
    solve_rst(s0, bc);
#pragma unroll
    for (int k = 0; k < 16; ++k) bcs[k] = bc[k];
  }
  __syncthreads();
  const float sc = bcs[9];
  const float e0 = sc * (bcs[0] * sx + bcs[1] * sy + bcs[2] * sz) + bcs[10] - dx;
  const float e1 = sc * (bcs[3] * sx + bcs[4] * sy + bcs[5] * sz) + bcs[11] - dy;
  const float e2 = sc * (bcs[6] * sx + bcs[7] * sy + bcs[8] * sz) + bcs[12] - dz;
  float acc = fabsf(e0) + fabsf(e1) + fabsf(e2);
  acc = wredf(acc);
  __shared__ float red2[4];
  if (lane == 0) red2[wv] = acc;
  __syncthreads();
  if (t == 0) partials[b] = (red2[0] + red2[1]) + (red2[2] + red2[3]);
}

extern "C" void kernel_launch(void* const* d_in, const int* in_sizes, int n_in,
                              void* d_out, int out_size, void* d_ws, size_t ws_size,
                              hipStream_t stream) {
  const float* kp = (const float*)d_in[0];
  const int* perm = (const int*)d_in[1];
  float* out = (float*)d_out;
  const int B = in_sizes[1];
  const double inv_total = 1.0 / ((double)B * (double)GEO_N * 3.0);

  const size_t need = (size_t)B * (16 + 16 + 1) * sizeof(float);
  if (ws_size >= need) {
    float* moments = (float*)d_ws;                 // B*16
    float* params = moments + (size_t)B * 16;      // B*16
    float* partials = params + (size_t)B * 16;     // B
    const int gridW = (B + 3) / 4;                 // one wave per batch, 4/block
    geo_moments<<<gridW, 256, 0, stream>>>(kp, perm, moments, B);
    geo_svd<<<(B + 255) / 256, 256, 0, stream>>>(moments, params, B);
    geo_err<<<gridW, 256, 0, stream>>>(kp, perm, params, partials, B);
    geo_fin<<<1, 1024, 0, stream>>>(partials, out, B, inv_total);
  } else if (ws_size >= (size_t)B * sizeof(float)) {
    float* partials = (float*)d_ws;
    geo_fused<<<B, 256, 0, stream>>>(kp, perm, partials);
    geo_fin<<<1, 1024, 0, stream>>>(partials, out, B, inv_total);
  }
}